// Round 1
// 9544.099 us; speedup vs baseline: 1.9549x; 1.9549x over previous
//
#include <hip/hip_runtime.h>
#include <hip/hip_bf16.h>
#include <stdint.h>

#define NN 150000
#define NE 150000
#define G 128
#define D 512
#define L 5
#define MAXD 20
#define EPS 1e-5f
#define NB ((NN + 255) / 256)

typedef unsigned short u16;
typedef unsigned int u32;
typedef __attribute__((ext_vector_type(8))) short bf16x8;
typedef __attribute__((ext_vector_type(4))) float f32x4;

__device__ __forceinline__ float bf2f(u16 u) {
    union { u32 i; float f; } v; v.i = ((u32)u) << 16; return v.f;
}
__device__ __forceinline__ u16 f2bf(float f) {
    union { float f; u32 i; } v; v.f = f;
    u32 r = v.i + 0x7FFF + ((v.i >> 16) & 1);
    return (u16)(r >> 16);
}
// split fp32 -> (hi, lo) bf16 pair
__device__ __forceinline__ void split2(float v, u16& hi, u16& lo) {
    hi = f2bf(v);
    lo = f2bf(v - bf2f(hi));
}

// ---------------- zero fill ----------------
__global__ void k_zero(float* __restrict__ p, int n) {
    int i = blockIdx.x * 256 + threadIdx.x;
    if (i < n) p[i] = 0.0f;
}

// ---------------- degree (out-degree by row, used for norm + self term) ----
__global__ void k_deg_count(const int* __restrict__ row, int* __restrict__ degint) {
    int e = blockIdx.x * 256 + threadIdx.x;
    if (e < NE) atomicAdd(&degint[row[e]], 1);
}
__global__ void k_deg_fin(const int* __restrict__ degint, float* __restrict__ deg,
                          float* __restrict__ dis) {
    int n = blockIdx.x * 256 + threadIdx.x;
    if (n < NN) {
        float d = (float)degint[n] + 1.0f;
        deg[n] = d;
        dis[n] = rsqrtf(d);
    }
}

// ---------------- CSR build by destination (col) -----------------------------
__global__ void k_incount(const int* __restrict__ col, int* __restrict__ incnt) {
    int e = blockIdx.x * 256 + threadIdx.x;
    if (e < NE) atomicAdd(&incnt[col[e]], 1);
}
__global__ void k_scan1(const int* __restrict__ incnt, int* __restrict__ bsum) {
    __shared__ int sm[256];
    int b = blockIdx.x, t = threadIdx.x;
    int n = b * 256 + t;
    sm[t] = (n < NN) ? incnt[n] : 0;
    __syncthreads();
    #pragma unroll
    for (int s = 128; s > 0; s >>= 1) {
        if (t < s) sm[t] += sm[t + s];
        __syncthreads();
    }
    if (t == 0) bsum[b] = sm[0];
}
__global__ void k_scan2(const int* __restrict__ bsum, int* __restrict__ boff) {
    __shared__ int sm[1024];
    int t = threadIdx.x;
    int v0 = (t < NB) ? bsum[t] : 0;
    sm[t] = v0;
    __syncthreads();
    #pragma unroll
    for (int s = 1; s < 1024; s <<= 1) {
        int v = (t >= s) ? sm[t - s] : 0;
        __syncthreads();
        sm[t] += v;
        __syncthreads();
    }
    if (t < NB) boff[t] = sm[t] - v0;  // exclusive
}
__global__ void k_scan3(const int* __restrict__ incnt, const int* __restrict__ boff,
                        int* __restrict__ off, int* __restrict__ cursor) {
    __shared__ int sm[256];
    int b = blockIdx.x, t = threadIdx.x;
    int n = b * 256 + t;
    int c = (n < NN) ? incnt[n] : 0;
    sm[t] = c;
    __syncthreads();
    #pragma unroll
    for (int s = 1; s < 256; s <<= 1) {
        int v = (t >= s) ? sm[t - s] : 0;
        __syncthreads();
        sm[t] += v;
        __syncthreads();
    }
    if (n < NN) {
        int ex = boff[b] + sm[t] - c;
        off[n] = ex;
        cursor[n] = ex;
    }
}
// elist entry: (src as int bits, norm, a0, a1)
__global__ void k_fill(const int* __restrict__ row, const int* __restrict__ col,
                       const float* __restrict__ ea, const float* __restrict__ dis,
                       int* __restrict__ cursor, float4* __restrict__ elist) {
    int e = blockIdx.x * 256 + threadIdx.x;
    if (e >= NE) return;
    int r = row[e], c = col[e];
    int pos = atomicAdd(&cursor[c], 1);
    float4 v;
    v.x = __int_as_float(r);
    v.y = dis[r] * dis[c];
    v.z = ea[2 * e];
    v.w = ea[2 * e + 1];
    elist[pos] = v;
}

// ---------------- node encoder (fp32 in, hi/lo bf16 out) ----------------
__global__ void k_encoder(const int* __restrict__ x, const int* __restrict__ dep,
                          const float* __restrict__ te, const float* __restrict__ ae,
                          const float* __restrict__ de,
                          u16* __restrict__ hh, u16* __restrict__ hl) {
    int n = blockIdx.x, t = threadIdx.x;  // 256 threads, 2 cols each
    int t0 = x[2 * n], t1 = x[2 * n + 1];
    int dp = dep[n]; if (dp > MAXD) dp = MAXD;
    float2 a = ((const float2*)(te + (size_t)t0 * D))[t];
    float2 b = ((const float2*)(ae + (size_t)t1 * D))[t];
    float2 c = ((const float2*)(de + (size_t)dp * D))[t];
    float v0 = a.x + b.x + c.x;
    float v1 = a.y + b.y + c.y;
    u16 h0, l0, h1, l1;
    split2(v0, h0, l0); split2(v1, h1, l1);
    ((u32*)(hh + (size_t)n * D))[t] = (u32)h0 | ((u32)h1 << 16);
    ((u32*)(hl + (size_t)n * D))[t] = (u32)l0 | ((u32)l1 << 16);
}

// -------- transpose+split lin_w: Wh/Wl[l][n][k] = split(W[l][k][n]) --------
__global__ void k_wsplit(const float* __restrict__ W, u16* __restrict__ Wh,
                         u16* __restrict__ Wl) {
    __shared__ float tile[32][33];
    int l = blockIdx.z, kt = blockIdx.y, nt = blockIdx.x;
    const float* Wlp = W + (size_t)l * D * D;
    int tx = threadIdx.x, ty = threadIdx.y;  // 32 x 8
    #pragma unroll
    for (int i = 0; i < 32; i += 8)
        tile[ty + i][tx] = Wlp[(size_t)(kt * 32 + ty + i) * D + nt * 32 + tx];
    __syncthreads();
    #pragma unroll
    for (int i = 0; i < 32; i += 8) {
        float v = tile[tx][ty + i];
        u16 hi, lo; split2(v, hi, lo);
        size_t o = (size_t)l * D * D + (size_t)(nt * 32 + ty + i) * D + kt * 32 + tx;
        Wh[o] = hi; Wl[o] = lo;
    }
}

// ---------------- vn init ----------------
__global__ void k_vninit(const float* __restrict__ vw, float* __restrict__ vn) {
    int i = blockIdx.x * 256 + threadIdx.x;
    vn[i] = vw[i & (D - 1)];
}

// ---------------- vnW = vn @ W + lin_b (fp32, tiny) ----------------
__global__ void k_vnw(const float* __restrict__ vn, const float* __restrict__ W,
                      const float* __restrict__ lb, float* __restrict__ vnW) {
    int g = blockIdx.x, c = threadIdx.x;  // 512 threads
    __shared__ float sv[D];
    sv[c] = vn[g * D + c];
    __syncthreads();
    float acc = lb[c];
    for (int k = 0; k < D; k++) acc = fmaf(sv[k], W[(size_t)k * D + c], acc);
    vnW[g * D + c] = acc;
}

// ------- split-bf16 GEMM: hx = (hh+hl) @ (Wh+Wl)^T_layout + vnW[batch] -----
// 3 MFMA products per tile: Ah*Bh + Ah*Bl + Al*Bh (Al*Bl dropped, ~2^-18)
__global__ __launch_bounds__(256) void k_gemm3(
    const u16* __restrict__ Ahp, const u16* __restrict__ Alp,
    const u16* __restrict__ Bhp, const u16* __restrict__ Blp,
    const float* __restrict__ vnW, const int* __restrict__ batch,
    float* __restrict__ hx) {
    __shared__ __align__(16) u16 sAh[128 * 32];
    __shared__ __align__(16) u16 sAl[128 * 32];
    __shared__ __align__(16) u16 sBh[128 * 32];
    __shared__ __align__(16) u16 sBl[128 * 32];
    const int tid = threadIdx.x;
    const int wave = tid >> 6, ln = tid & 63;
    const long row0 = (long)blockIdx.x * 128;
    const int col0 = blockIdx.y * 128;

    f32x4 acc[4][4] = {};
    const int wm = wave & 1, wn = wave >> 1;
    const int lrow = ln & 15, lq = ln >> 4, lk = (ln >> 4) * 8;

    int s_row[2], s_col[2];
    #pragma unroll
    for (int i = 0; i < 2; i++) {
        int idx = tid + 256 * i;          // 512 chunks of 8 u16 = one 128x32 tile
        s_row[i] = idx >> 2;
        s_col[i] = (idx & 3) * 8;
    }

    for (int kt = 0; kt < D / 32; ++kt) {
        uint4 vah[2], val[2], vbh[2], vbl[2];
        #pragma unroll
        for (int i = 0; i < 2; i++) {
            long ar = row0 + s_row[i];
            if (ar >= NN) ar = NN - 1;    // clamp (stores guarded)
            size_t ao = (size_t)ar * D + kt * 32 + s_col[i];
            size_t bo = (size_t)(col0 + s_row[i]) * D + kt * 32 + s_col[i];
            vah[i] = *(const uint4*)(Ahp + ao);
            val[i] = *(const uint4*)(Alp + ao);
            vbh[i] = *(const uint4*)(Bhp + bo);
            vbl[i] = *(const uint4*)(Blp + bo);
        }
        __syncthreads();
        #pragma unroll
        for (int i = 0; i < 2; i++) {
            int o = s_row[i] * 32 + s_col[i];
            *(uint4*)&sAh[o] = vah[i];
            *(uint4*)&sAl[o] = val[i];
            *(uint4*)&sBh[o] = vbh[i];
            *(uint4*)&sBl[o] = vbl[i];
        }
        __syncthreads();
        bf16x8 ah[4], al[4], bh[4], bl[4];
        #pragma unroll
        for (int i = 0; i < 4; i++) {
            int ao = (wm * 64 + i * 16 + lrow) * 32 + lk;
            int bo = (wn * 64 + i * 16 + lrow) * 32 + lk;
            ah[i] = *(const bf16x8*)&sAh[ao];
            al[i] = *(const bf16x8*)&sAl[ao];
            bh[i] = *(const bf16x8*)&sBh[bo];
            bl[i] = *(const bf16x8*)&sBl[bo];
        }
        #pragma unroll
        for (int i = 0; i < 4; i++) {
            #pragma unroll
            for (int j = 0; j < 4; j++) {
                acc[i][j] = __builtin_amdgcn_mfma_f32_16x16x32_bf16(ah[i], bh[j], acc[i][j], 0, 0, 0);
                acc[i][j] = __builtin_amdgcn_mfma_f32_16x16x32_bf16(ah[i], bl[j], acc[i][j], 0, 0, 0);
                acc[i][j] = __builtin_amdgcn_mfma_f32_16x16x32_bf16(al[i], bh[j], acc[i][j], 0, 0, 0);
            }
        }
    }
    // C/D layout: col = lane&15, row = (lane>>4)*4 + reg  (validated round 3)
    #pragma unroll
    for (int i = 0; i < 4; i++) {
        #pragma unroll
        for (int r = 0; r < 4; r++) {
            long R = row0 + wm * 64 + i * 16 + lq * 4 + r;
            if (R < NN) {
                int g = batch[R];
                const float* vrow = vnW + g * D;
                #pragma unroll
                for (int j = 0; j < 4; j++) {
                    int Cc = col0 + wn * 64 + j * 16 + lrow;
                    hx[(size_t)R * D + Cc] = acc[i][j][r] + vrow[Cc];
                }
            }
        }
    }
}

// ------- fused aggregate: acc[n] = relu(hx[n]+cb)/deg[n]
//                                 + sum_{e: col[e]==n} nrm_e * relu(hx[row_e] + ee_e)
// also accumulates BN sum/sumsq (block-reduced in LDS, 1 atomic/col/block) -----
__global__ __launch_bounds__(256) void k_aggr(
    const int* __restrict__ off, const int* __restrict__ cnt,
    const float4* __restrict__ elist, const float* __restrict__ hx,
    const float* __restrict__ cb, const float* __restrict__ deg,
    const float* __restrict__ ew, const float* __restrict__ eb,
    float* __restrict__ out, float* __restrict__ bns) {
    const int lane = threadIdx.x & 63;
    const int wv = threadIdx.x >> 6;
    const int gw = blockIdx.x * 4 + wv;
    const int nwaves = gridDim.x * 4;
    const int c0 = lane * 8;

    float w0[8], w1[8], bb[8], cbv[8];
    *(float4*)&w0[0] = *(const float4*)(ew + c0);
    *(float4*)&w0[4] = *(const float4*)(ew + c0 + 4);
    *(float4*)&w1[0] = *(const float4*)(ew + D + c0);
    *(float4*)&w1[4] = *(const float4*)(ew + D + c0 + 4);
    *(float4*)&bb[0] = *(const float4*)(eb + c0);
    *(float4*)&bb[4] = *(const float4*)(eb + c0 + 4);
    *(float4*)&cbv[0] = *(const float4*)(cb + c0);
    *(float4*)&cbv[4] = *(const float4*)(cb + c0 + 4);

    float s[8] = {}, q[8] = {};

    for (int n = gw; n < NN; n += nwaves) {
        float a[8];
        const float* hp = hx + (size_t)n * D + c0;
        *(float4*)&a[0] = *(const float4*)(hp);
        *(float4*)&a[4] = *(const float4*)(hp + 4);
        float invd = 1.0f / deg[n];
        float acc8[8];
        #pragma unroll
        for (int j = 0; j < 8; j++) acc8[j] = fmaxf(a[j] + cbv[j], 0.0f) * invd;

        int k0 = off[n], k1 = k0 + cnt[n];
        for (int k = k0; k < k1; k++) {
            float4 m = elist[k];
            int r = __float_as_int(m.x);
            const float* hr = hx + (size_t)r * D + c0;
            float hf[8];
            *(float4*)&hf[0] = *(const float4*)(hr);
            *(float4*)&hf[4] = *(const float4*)(hr + 4);
            #pragma unroll
            for (int j = 0; j < 8; j++)
                acc8[j] = fmaf(m.y, fmaxf(hf[j] + fmaf(m.z, w0[j], fmaf(m.w, w1[j], bb[j])), 0.0f), acc8[j]);
        }
        float* op = out + (size_t)n * D + c0;
        *(float4*)(op) = *(const float4*)&acc8[0];
        *(float4*)(op + 4) = *(const float4*)&acc8[4];
        #pragma unroll
        for (int j = 0; j < 8; j++) {
            s[j] += acc8[j];
            q[j] = fmaf(acc8[j], acc8[j], q[j]);
        }
    }

    // block-level BN reduction: 4 waves share the same column mapping
    __shared__ float red[4][512];
    #pragma unroll
    for (int j = 0; j < 8; j++) red[wv][c0 + j] = s[j];
    __syncthreads();
    if (wv == 0) {
        #pragma unroll
        for (int j = 0; j < 8; j++) {
            int c = c0 + j;
            float t = red[0][c] + red[1][c] + red[2][c] + red[3][c];
            atomicAdd(&bns[c], t);
        }
    }
    __syncthreads();
    #pragma unroll
    for (int j = 0; j < 8; j++) red[wv][c0 + j] = q[j];
    __syncthreads();
    if (wv == 0) {
        #pragma unroll
        for (int j = 0; j < 8; j++) {
            int c = c0 + j;
            float t = red[0][c] + red[1][c] + red[2][c] + red[3][c];
            atomicAdd(&bns[D + c], t);
        }
    }
}

// ---------------- BN finalize ----------------
__global__ void k_bnfin(const float* __restrict__ sums, const float* __restrict__ g,
                        const float* __restrict__ b, float* __restrict__ sc,
                        float* __restrict__ sh) {
    int c = threadIdx.x;  // 512
    float mu = sums[c] * (1.0f / NN);
    float var = fmaxf(sums[D + c] * (1.0f / NN) - mu * mu, 0.0f);
    float rstd = rsqrtf(var + EPS);
    float scale = rstd * g[c];
    sc[c] = scale;
    sh[c] = b[c] - mu * scale;
}

// ------- BN apply + relu + pool; write h as hi/lo bf16 pair (internal) ------
__global__ void k_final(const float* __restrict__ accb, const float* __restrict__ sc,
                        const float* __restrict__ sh, const int* __restrict__ batch,
                        u16* __restrict__ hh, u16* __restrict__ hl,
                        float* __restrict__ pool) {
    int t = threadIdx.x; int c = 2 * t;
    long n0 = (long)blockIdx.x * 256;
    float s0 = sc[c], s1 = sc[c + 1], h0 = sh[c], h1 = sh[c + 1];
    float p0 = 0, p1 = 0; int gc = -1;
    for (int rI = 0; rI < 256; rI++) {
        long n = n0 + rI; if (n >= NN) break;
        float2 v = *(const float2*)(accb + (size_t)n * D + c);
        float a = fmaxf(fmaf(v.x, s0, h0), 0.0f);
        float b = fmaxf(fmaf(v.y, s1, h1), 0.0f);
        u16 ah, al, bh, bl;
        split2(a, ah, al); split2(b, bh, bl);
        ((u32*)(hh + (size_t)n * D))[t] = (u32)ah | ((u32)bh << 16);
        ((u32*)(hl + (size_t)n * D))[t] = (u32)al | ((u32)bl << 16);
        int g = batch[n];
        if (g != gc) {
            if (gc >= 0) { atomicAdd(&pool[gc * D + c], p0); atomicAdd(&pool[gc * D + c + 1], p1); }
            gc = g; p0 = 0; p1 = 0;
        }
        p0 += a; p1 += b;
    }
    if (gc >= 0) { atomicAdd(&pool[gc * D + c], p0); atomicAdd(&pool[gc * D + c + 1], p1); }
}

// ---------------- BN apply, write d_out fp32 (last layer) ----------------
__global__ void k_finalout(const float* __restrict__ accb, const float* __restrict__ sc,
                           const float* __restrict__ sh, float* __restrict__ out) {
    int t = threadIdx.x; int c = 2 * t;
    long n0 = (long)blockIdx.x * 256;
    float s0 = sc[c], s1 = sc[c + 1], h0 = sh[c], h1 = sh[c + 1];
    for (int rI = 0; rI < 256; rI++) {
        long n = n0 + rI; if (n >= NN) break;
        float2 v = *(const float2*)(accb + (size_t)n * D + c);
        ((float2*)out)[n * 256 + t] = make_float2(fmaf(v.x, s0, h0), fmaf(v.y, s1, h1));
    }
}

// ---------------- virtual-node MLP (fp32) ----------------
__global__ void k_mlp1(const float* __restrict__ vn, const float* __restrict__ pool,
                       const float* __restrict__ w1, const float* __restrict__ b1,
                       float* __restrict__ u) {
    int g = blockIdx.x >> 2;
    int j = ((blockIdx.x & 3) << 8) | threadIdx.x;
    __shared__ float sv[D];
    int t = threadIdx.x;
    sv[t] = vn[g * D + t] + pool[g * D + t];
    sv[t + 256] = vn[g * D + t + 256] + pool[g * D + t + 256];
    __syncthreads();
    float acc = b1[j];
    for (int k = 0; k < D; k++) acc = fmaf(sv[k], w1[(size_t)k * 2 * D + j], acc);
    u[(size_t)g * 2 * D + j] = acc;
}
__global__ void k_mbn(const float* __restrict__ u, const float* __restrict__ mg,
                      const float* __restrict__ mb, float* __restrict__ z) {
    int j = blockIdx.x * 256 + threadIdx.x;  // 1024 total
    float s = 0, q = 0;
    for (int g = 0; g < G; g++) { float v = u[(size_t)g * 2 * D + j]; s += v; q = fmaf(v, v, q); }
    float mu = s * (1.0f / G);
    float var = fmaxf(q * (1.0f / G) - mu * mu, 0.0f);
    float rstd = rsqrtf(var + EPS);
    float sc = rstd * mg[j];
    float sh = mb[j] - mu * sc;
    for (int g = 0; g < G; g++)
        z[(size_t)g * 2 * D + j] = fmaxf(fmaf(u[(size_t)g * 2 * D + j], sc, sh), 0.0f);
}
__global__ void k_mlp2(const float* __restrict__ z, const float* __restrict__ w2,
                       const float* __restrict__ b2, float* __restrict__ vn) {
    int g = blockIdx.x >> 1;
    int c = ((blockIdx.x & 1) << 8) | threadIdx.x;
    __shared__ float sz[2 * D];
    int t = threadIdx.x;
    #pragma unroll
    for (int i = 0; i < 4; i++) sz[t + i * 256] = z[(size_t)g * 2 * D + t + i * 256];
    __syncthreads();
    float acc = b2[c];
    for (int k = 0; k < 2 * D; k++) acc = fmaf(sz[k], w2[(size_t)k * D + c], acc);
    vn[g * D + c] = acc;
}

extern "C" void kernel_launch(void* const* d_in, const int* in_sizes, int n_in,
                              void* d_out, int out_size, void* d_ws, size_t ws_size,
                              hipStream_t stream) {
    (void)in_sizes; (void)n_in; (void)out_size; (void)ws_size;
    const int*   x     = (const int*)d_in[0];
    const int*   ndep  = (const int*)d_in[1];
    const int*   ei    = (const int*)d_in[2];
    const int*   batch = (const int*)d_in[3];
    const float* ea    = (const float*)d_in[4];
    const float* te    = (const float*)d_in[5];
    const float* ae    = (const float*)d_in[6];
    const float* de    = (const float*)d_in[7];
    const float* vw    = (const float*)d_in[8];
    const float* lw    = (const float*)d_in[9];
    const float* lb    = (const float*)d_in[10];
    const float* cb    = (const float*)d_in[11];
    const float* ew    = (const float*)d_in[12];
    const float* ebp   = (const float*)d_in[13];
    const float* bng   = (const float*)d_in[14];
    const float* bnb   = (const float*)d_in[15];
    const float* mw1   = (const float*)d_in[16];
    const float* mb1   = (const float*)d_in[17];
    const float* mg    = (const float*)d_in[18];
    const float* mbb   = (const float*)d_in[19];
    const float* mw2   = (const float*)d_in[20];
    const float* mb2   = (const float*)d_in[21];

    char* ws = (char*)d_ws;
    size_t off_ = 0;
    auto alloc = [&](size_t b) { size_t o = off_; off_ += (b + 255) & ~(size_t)255; return o; };
    u16*  hh   = (u16*)(ws + alloc((size_t)NN * D * 2));
    u16*  hl   = (u16*)(ws + alloc((size_t)NN * D * 2));
    float* hx  = (float*)(ws + alloc((size_t)NN * D * 4));
    float* acc = (float*)(ws + alloc((size_t)NN * D * 4));
    u16*  Wth  = (u16*)(ws + alloc((size_t)L * D * D * 2));
    u16*  Wtl  = (u16*)(ws + alloc((size_t)L * D * D * 2));
    float* vnW = (float*)(ws + alloc((size_t)G * D * 4));
    float* vn  = (float*)(ws + alloc((size_t)G * D * 4));
    float* pool= (float*)(ws + alloc((size_t)G * D * 4));
    float* u   = (float*)(ws + alloc((size_t)G * 2 * D * 4));
    float* z   = (float*)(ws + alloc((size_t)G * 2 * D * 4));
    float* deg = (float*)(ws + alloc((size_t)NN * 4));
    float* dis = (float*)(ws + alloc((size_t)NN * 4));
    int* degint= (int*)(ws + alloc((size_t)NN * 4));
    float* bns = (float*)(ws + alloc((size_t)2 * D * 4));
    float* bsc = (float*)(ws + alloc((size_t)D * 4));
    float* bsh = (float*)(ws + alloc((size_t)D * 4));
    // CSR-by-destination structures (graph is layer-invariant -> build once)
    int* incnt  = (int*)(ws + alloc((size_t)NN * 4));
    int* offp   = (int*)(ws + alloc((size_t)NN * 4));
    int* cursor = (int*)(ws + alloc((size_t)NN * 4));
    int* bsum   = (int*)(ws + alloc((size_t)1024 * 4));
    int* boff   = (int*)(ws + alloc((size_t)1024 * 4));
    float4* elist = (float4*)(ws + alloc((size_t)NE * 16));

    const int* row = ei;
    const int* colp = ei + NE;

    k_zero<<<(NN + 255) / 256, 256, 0, stream>>>((float*)degint, NN);
    k_deg_count<<<(NE + 255) / 256, 256, 0, stream>>>(row, degint);
    k_deg_fin<<<(NN + 255) / 256, 256, 0, stream>>>(degint, deg, dis);

    // build destination CSR (once)
    k_zero<<<(NN + 255) / 256, 256, 0, stream>>>((float*)incnt, NN);
    k_incount<<<(NE + 255) / 256, 256, 0, stream>>>(colp, incnt);
    k_scan1<<<NB, 256, 0, stream>>>(incnt, bsum);
    k_scan2<<<1, 1024, 0, stream>>>(bsum, boff);
    k_scan3<<<NB, 256, 0, stream>>>(incnt, boff, offp, cursor);
    k_fill<<<(NE + 255) / 256, 256, 0, stream>>>(row, colp, ea, dis, cursor, elist);

    k_encoder<<<NN, 256, 0, stream>>>(x, ndep, te, ae, de, hh, hl);
    k_wsplit<<<dim3(16, 16, L), dim3(32, 8), 0, stream>>>(lw, Wth, Wtl);
    k_vninit<<<G * D / 256, 256, 0, stream>>>(vw, vn);

    for (int l = 0; l < L; l++) {
        k_vnw<<<G, 512, 0, stream>>>(vn, lw + (size_t)l * D * D, lb + (size_t)l * D, vnW);
        k_gemm3<<<dim3((NN + 127) / 128, 4), 256, 0, stream>>>(
            hh, hl, Wth + (size_t)l * D * D, Wtl + (size_t)l * D * D, vnW, batch, hx);
        k_zero<<<4, 256, 0, stream>>>(bns, 2 * D);
        k_aggr<<<2048, 256, 0, stream>>>(offp, incnt, elist, hx, cb + (size_t)l * D,
                                         deg, ew + (size_t)l * 2 * D,
                                         ebp + (size_t)l * D, acc, bns);
        k_bnfin<<<1, D, 0, stream>>>(bns, bng + (size_t)l * D, bnb + (size_t)l * D, bsc, bsh);
        if (l < L - 1) {
            k_zero<<<G * D / 256, 256, 0, stream>>>(pool, G * D);
            k_final<<<(NN + 255) / 256, 256, 0, stream>>>(acc, bsc, bsh, batch, hh, hl, pool);
            k_mlp1<<<G * 4, 256, 0, stream>>>(vn, pool, mw1 + (size_t)l * D * 2 * D,
                                              mb1 + (size_t)l * 2 * D, u);
            k_mbn<<<4, 256, 0, stream>>>(u, mg + (size_t)l * 2 * D, mbb + (size_t)l * 2 * D, z);
            k_mlp2<<<G * 2, 256, 0, stream>>>(z, mw2 + (size_t)l * 2 * D * D,
                                              mb2 + (size_t)l * D, vn);
        } else {
            k_finalout<<<(NN + 255) / 256, 256, 0, stream>>>(acc, bsc, bsh, (float*)d_out);
        }
    }
}

// Round 2
// 8927.022 us; speedup vs baseline: 2.0900x; 1.0691x over previous
//
#include <hip/hip_runtime.h>
#include <hip/hip_bf16.h>
#include <stdint.h>

#define NN 150000
#define NE 150000
#define G 128
#define D 512
#define L 5
#define MAXD 20
#define EPS 1e-5f
#define NB ((NN + 255) / 256)

typedef unsigned short u16;
typedef unsigned int u32;
typedef __attribute__((ext_vector_type(8))) short bf16x8;
typedef __attribute__((ext_vector_type(4))) float f32x4;

__device__ __forceinline__ float bf2f(u16 u) {
    union { u32 i; float f; } v; v.i = ((u32)u) << 16; return v.f;
}
__device__ __forceinline__ u16 f2bf(float f) {
    union { float f; u32 i; } v; v.f = f;
    u32 r = v.i + 0x7FFF + ((v.i >> 16) & 1);
    return (u16)(r >> 16);
}
// split fp32 -> (hi, lo) bf16 pair
__device__ __forceinline__ void split2(float v, u16& hi, u16& lo) {
    hi = f2bf(v);
    lo = f2bf(v - bf2f(hi));
}

// ---------------- zero fill ----------------
__global__ void k_zero(float* __restrict__ p, int n) {
    int i = blockIdx.x * 256 + threadIdx.x;
    if (i < n) p[i] = 0.0f;
}

// ---------------- degree (out-degree by row, used for norm + self term) ----
__global__ void k_deg_count(const int* __restrict__ row, int* __restrict__ degint) {
    int e = blockIdx.x * 256 + threadIdx.x;
    if (e < NE) atomicAdd(&degint[row[e]], 1);
}
__global__ void k_deg_fin(const int* __restrict__ degint, float* __restrict__ deg,
                          float* __restrict__ dis) {
    int n = blockIdx.x * 256 + threadIdx.x;
    if (n < NN) {
        float d = (float)degint[n] + 1.0f;
        deg[n] = d;
        dis[n] = rsqrtf(d);
    }
}

// ---------------- CSR build by destination (col) -----------------------------
__global__ void k_incount(const int* __restrict__ col, int* __restrict__ incnt) {
    int e = blockIdx.x * 256 + threadIdx.x;
    if (e < NE) atomicAdd(&incnt[col[e]], 1);
}
__global__ void k_scan1(const int* __restrict__ incnt, int* __restrict__ bsum) {
    __shared__ int sm[256];
    int b = blockIdx.x, t = threadIdx.x;
    int n = b * 256 + t;
    sm[t] = (n < NN) ? incnt[n] : 0;
    __syncthreads();
    #pragma unroll
    for (int s = 128; s > 0; s >>= 1) {
        if (t < s) sm[t] += sm[t + s];
        __syncthreads();
    }
    if (t == 0) bsum[b] = sm[0];
}
__global__ void k_scan2(const int* __restrict__ bsum, int* __restrict__ boff) {
    __shared__ int sm[1024];
    int t = threadIdx.x;
    int v0 = (t < NB) ? bsum[t] : 0;
    sm[t] = v0;
    __syncthreads();
    #pragma unroll
    for (int s = 1; s < 1024; s <<= 1) {
        int v = (t >= s) ? sm[t - s] : 0;
        __syncthreads();
        sm[t] += v;
        __syncthreads();
    }
    if (t < NB) boff[t] = sm[t] - v0;  // exclusive
}
__global__ void k_scan3(const int* __restrict__ incnt, const int* __restrict__ boff,
                        int* __restrict__ off, int* __restrict__ cursor) {
    __shared__ int sm[256];
    int b = blockIdx.x, t = threadIdx.x;
    int n = b * 256 + t;
    int c = (n < NN) ? incnt[n] : 0;
    sm[t] = c;
    __syncthreads();
    #pragma unroll
    for (int s = 1; s < 256; s <<= 1) {
        int v = (t >= s) ? sm[t - s] : 0;
        __syncthreads();
        sm[t] += v;
        __syncthreads();
    }
    if (n < NN) {
        int ex = boff[b] + sm[t] - c;
        off[n] = ex;
        cursor[n] = ex;
    }
}
// elist entry: (src as int bits, norm, a0, a1)
__global__ void k_fill(const int* __restrict__ row, const int* __restrict__ col,
                       const float* __restrict__ ea, const float* __restrict__ dis,
                       int* __restrict__ cursor, float4* __restrict__ elist) {
    int e = blockIdx.x * 256 + threadIdx.x;
    if (e >= NE) return;
    int r = row[e], c = col[e];
    int pos = atomicAdd(&cursor[c], 1);
    float4 v;
    v.x = __int_as_float(r);
    v.y = dis[r] * dis[c];
    v.z = ea[2 * e];
    v.w = ea[2 * e + 1];
    elist[pos] = v;
}

// ---------------- node encoder (fp32 in, hi/lo bf16 out) ----------------
__global__ void k_encoder(const int* __restrict__ x, const int* __restrict__ dep,
                          const float* __restrict__ te, const float* __restrict__ ae,
                          const float* __restrict__ de,
                          u16* __restrict__ hh, u16* __restrict__ hl) {
    int n = blockIdx.x, t = threadIdx.x;  // 256 threads, 2 cols each
    int t0 = x[2 * n], t1 = x[2 * n + 1];
    int dp = dep[n]; if (dp > MAXD) dp = MAXD;
    float2 a = ((const float2*)(te + (size_t)t0 * D))[t];
    float2 b = ((const float2*)(ae + (size_t)t1 * D))[t];
    float2 c = ((const float2*)(de + (size_t)dp * D))[t];
    float v0 = a.x + b.x + c.x;
    float v1 = a.y + b.y + c.y;
    u16 h0, l0, h1, l1;
    split2(v0, h0, l0); split2(v1, h1, l1);
    ((u32*)(hh + (size_t)n * D))[t] = (u32)h0 | ((u32)h1 << 16);
    ((u32*)(hl + (size_t)n * D))[t] = (u32)l0 | ((u32)l1 << 16);
}

// -------- transpose+split lin_w: Wh/Wl[l][n][k] = split(W[l][k][n]) --------
__global__ void k_wsplit(const float* __restrict__ W, u16* __restrict__ Wh,
                         u16* __restrict__ Wl) {
    __shared__ float tile[32][33];
    int l = blockIdx.z, kt = blockIdx.y, nt = blockIdx.x;
    const float* Wlp = W + (size_t)l * D * D;
    int tx = threadIdx.x, ty = threadIdx.y;  // 32 x 8
    #pragma unroll
    for (int i = 0; i < 32; i += 8)
        tile[ty + i][tx] = Wlp[(size_t)(kt * 32 + ty + i) * D + nt * 32 + tx];
    __syncthreads();
    #pragma unroll
    for (int i = 0; i < 32; i += 8) {
        float v = tile[tx][ty + i];
        u16 hi, lo; split2(v, hi, lo);
        size_t o = (size_t)l * D * D + (size_t)(nt * 32 + ty + i) * D + kt * 32 + tx;
        Wh[o] = hi; Wl[o] = lo;
    }
}

// ---------------- vn init ----------------
__global__ void k_vninit(const float* __restrict__ vw, float* __restrict__ vn) {
    int i = blockIdx.x * 256 + threadIdx.x;
    vn[i] = vw[i & (D - 1)];
}

// ---------------- vnW = vn @ W + lin_b (fp32, tiny) ----------------
__global__ void k_vnw(const float* __restrict__ vn, const float* __restrict__ W,
                      const float* __restrict__ lb, float* __restrict__ vnW) {
    int g = blockIdx.x, c = threadIdx.x;  // 512 threads
    __shared__ float sv[D];
    sv[c] = vn[g * D + c];
    __syncthreads();
    float acc = lb[c];
    for (int k = 0; k < D; k++) acc = fmaf(sv[k], W[(size_t)k * D + c], acc);
    vnW[g * D + c] = acc;
}

// ------- split-bf16 GEMM: hx = (hh+hl) @ (Wh+Wl)^T_layout + vnW[batch] -----
// 3 MFMA products per tile: Ah*Bh + Ah*Bl + Al*Bh (Al*Bl dropped, ~2^-18)
// Epilogue: LDS fragment transpose -> float4 stores (full-line writes).
// Grid: 1-D 4688 with bijective XCD-chunked swizzle, col-block fastest
// inside each chunk so the 4 blocks sharing an A-tile co-run on one XCD.
__global__ __launch_bounds__(256) void k_gemm3(
    const u16* __restrict__ Ahp, const u16* __restrict__ Alp,
    const u16* __restrict__ Bhp, const u16* __restrict__ Blp,
    const float* __restrict__ vnW, const int* __restrict__ batch,
    float* __restrict__ hx) {
    __shared__ __align__(16) u16 smem[4 * 128 * 32];   // 32 KB, reused by epilogue
    u16* sAh = smem;
    u16* sAl = smem + 4096;
    u16* sBh = smem + 8192;
    u16* sBl = smem + 12288;

    const int tid = threadIdx.x;
    const int wave = tid >> 6, ln = tid & 63;

    // XCD-aware swizzle: 4688 = 8 * 586; y (col-block) fastest within chunk
    int wg = blockIdx.x;
    int gid = (wg & 7) * 586 + (wg >> 3);
    const long row0 = (long)(gid >> 2) * 128;
    const int col0 = (gid & 3) * 128;

    f32x4 acc[4][4] = {};
    const int wm = wave & 1, wn = wave >> 1;
    const int lrow = ln & 15, lq = ln >> 4, lk = (ln >> 4) * 8;

    int s_row[2], s_col[2];
    #pragma unroll
    for (int i = 0; i < 2; i++) {
        int idx = tid + 256 * i;          // 512 chunks of 8 u16 = one 128x32 tile
        s_row[i] = idx >> 2;
        s_col[i] = (idx & 3) * 8;
    }

    for (int kt = 0; kt < D / 32; ++kt) {
        uint4 vah[2], val[2], vbh[2], vbl[2];
        #pragma unroll
        for (int i = 0; i < 2; i++) {
            long ar = row0 + s_row[i];
            if (ar >= NN) ar = NN - 1;    // clamp (stores guarded)
            size_t ao = (size_t)ar * D + kt * 32 + s_col[i];
            size_t bo = (size_t)(col0 + s_row[i]) * D + kt * 32 + s_col[i];
            vah[i] = *(const uint4*)(Ahp + ao);
            val[i] = *(const uint4*)(Alp + ao);
            vbh[i] = *(const uint4*)(Bhp + bo);
            vbl[i] = *(const uint4*)(Blp + bo);
        }
        __syncthreads();
        #pragma unroll
        for (int i = 0; i < 2; i++) {
            int o = s_row[i] * 32 + s_col[i];
            *(uint4*)&sAh[o] = vah[i];
            *(uint4*)&sAl[o] = val[i];
            *(uint4*)&sBh[o] = vbh[i];
            *(uint4*)&sBl[o] = vbl[i];
        }
        __syncthreads();
        bf16x8 ah[4], al[4], bh[4], bl[4];
        #pragma unroll
        for (int i = 0; i < 4; i++) {
            int ao = (wm * 64 + i * 16 + lrow) * 32 + lk;
            int bo = (wn * 64 + i * 16 + lrow) * 32 + lk;
            ah[i] = *(const bf16x8*)&sAh[ao];
            al[i] = *(const bf16x8*)&sAl[ao];
            bh[i] = *(const bf16x8*)&sBh[bo];
            bl[i] = *(const bf16x8*)&sBl[bo];
        }
        #pragma unroll
        for (int i = 0; i < 4; i++) {
            #pragma unroll
            for (int j = 0; j < 4; j++) {
                acc[i][j] = __builtin_amdgcn_mfma_f32_16x16x32_bf16(ah[i], bh[j], acc[i][j], 0, 0, 0);
                acc[i][j] = __builtin_amdgcn_mfma_f32_16x16x32_bf16(ah[i], bl[j], acc[i][j], 0, 0, 0);
                acc[i][j] = __builtin_amdgcn_mfma_f32_16x16x32_bf16(al[i], bh[j], acc[i][j], 0, 0, 0);
            }
        }
    }

    // ---- epilogue: transpose fragments via LDS, store float4 per lane ----
    // C/D layout per 16x16 frag: col = lane&15, row = (lane>>4)*4 + reg
    __syncthreads();                       // staging reads done; safe to reuse LDS
    float* fsm = (float*)smem;
    const int ep_off = wave * (32 * 64);   // 8 KB per wave, 32 KB total
    const int rg = ln >> 4, cl = ln & 15;  // read-back: 16 lanes/row, 4 rows/instr
    #pragma unroll
    for (int ip = 0; ip < 2; ip++) {
        #pragma unroll
        for (int i2 = 0; i2 < 2; i2++) {
            int i = ip * 2 + i2;
            #pragma unroll
            for (int j = 0; j < 4; j++) {
                #pragma unroll
                for (int r = 0; r < 4; r++)
                    fsm[ep_off + (i2 * 16 + lq * 4 + r) * 64 + j * 16 + lrow] = acc[i][j][r];
            }
        }
        // same-wave LDS read-back (compiler inserts lgkmcnt waits)
        #pragma unroll
        for (int rr = 0; rr < 8; rr++) {
            int lr = rr * 4 + rg;          // local row 0..31
            int lc = cl * 4;               // local col 0..60
            long R = row0 + wm * 64 + ip * 32 + lr;
            if (R < NN) {
                float4 v = *(const float4*)&fsm[ep_off + lr * 64 + lc];
                int Cc = col0 + wn * 64 + lc;
                int g = batch[R];
                float4 b4 = *(const float4*)(vnW + (size_t)g * D + Cc);
                v.x += b4.x; v.y += b4.y; v.z += b4.z; v.w += b4.w;
                *(float4*)(hx + (size_t)R * D + Cc) = v;
            }
        }
        if (ip == 0) __syncthreads();      // not strictly needed (per-wave regions), cheap
    }
}

// ------- fused aggregate: acc[n] = relu(hx[n]+cb)/deg[n]
//                                 + sum_{e: col[e]==n} nrm_e * relu(hx[row_e] + ee_e)
// also accumulates BN sum/sumsq (block-reduced in LDS, 1 atomic/col/block) -----
__global__ __launch_bounds__(256) void k_aggr(
    const int* __restrict__ off, const int* __restrict__ cnt,
    const float4* __restrict__ elist, const float* __restrict__ hx,
    const float* __restrict__ cb, const float* __restrict__ deg,
    const float* __restrict__ ew, const float* __restrict__ eb,
    float* __restrict__ out, float* __restrict__ bns) {
    const int lane = threadIdx.x & 63;
    const int wv = threadIdx.x >> 6;
    const int gw = blockIdx.x * 4 + wv;
    const int nwaves = gridDim.x * 4;
    const int c0 = lane * 8;

    float w0[8], w1[8], bb[8], cbv[8];
    *(float4*)&w0[0] = *(const float4*)(ew + c0);
    *(float4*)&w0[4] = *(const float4*)(ew + c0 + 4);
    *(float4*)&w1[0] = *(const float4*)(ew + D + c0);
    *(float4*)&w1[4] = *(const float4*)(ew + D + c0 + 4);
    *(float4*)&bb[0] = *(const float4*)(eb + c0);
    *(float4*)&bb[4] = *(const float4*)(eb + c0 + 4);
    *(float4*)&cbv[0] = *(const float4*)(cb + c0);
    *(float4*)&cbv[4] = *(const float4*)(cb + c0 + 4);

    float s[8] = {}, q[8] = {};

    for (int n = gw; n < NN; n += nwaves) {
        float a[8];
        const float* hp = hx + (size_t)n * D + c0;
        *(float4*)&a[0] = *(const float4*)(hp);
        *(float4*)&a[4] = *(const float4*)(hp + 4);
        float invd = 1.0f / deg[n];
        float acc8[8];
        #pragma unroll
        for (int j = 0; j < 8; j++) acc8[j] = fmaxf(a[j] + cbv[j], 0.0f) * invd;

        int k0 = off[n], k1 = k0 + cnt[n];
        for (int k = k0; k < k1; k++) {
            float4 m = elist[k];
            int r = __float_as_int(m.x);
            const float* hr = hx + (size_t)r * D + c0;
            float hf[8];
            *(float4*)&hf[0] = *(const float4*)(hr);
            *(float4*)&hf[4] = *(const float4*)(hr + 4);
            #pragma unroll
            for (int j = 0; j < 8; j++)
                acc8[j] = fmaf(m.y, fmaxf(hf[j] + fmaf(m.z, w0[j], fmaf(m.w, w1[j], bb[j])), 0.0f), acc8[j]);
        }
        float* op = out + (size_t)n * D + c0;
        *(float4*)(op) = *(const float4*)&acc8[0];
        *(float4*)(op + 4) = *(const float4*)&acc8[4];
        #pragma unroll
        for (int j = 0; j < 8; j++) {
            s[j] += acc8[j];
            q[j] = fmaf(acc8[j], acc8[j], q[j]);
        }
    }

    // block-level BN reduction: 4 waves share the same column mapping
    __shared__ float red[4][512];
    #pragma unroll
    for (int j = 0; j < 8; j++) red[wv][c0 + j] = s[j];
    __syncthreads();
    if (wv == 0) {
        #pragma unroll
        for (int j = 0; j < 8; j++) {
            int c = c0 + j;
            float t = red[0][c] + red[1][c] + red[2][c] + red[3][c];
            atomicAdd(&bns[c], t);
        }
    }
    __syncthreads();
    #pragma unroll
    for (int j = 0; j < 8; j++) red[wv][c0 + j] = q[j];
    __syncthreads();
    if (wv == 0) {
        #pragma unroll
        for (int j = 0; j < 8; j++) {
            int c = c0 + j;
            float t = red[0][c] + red[1][c] + red[2][c] + red[3][c];
            atomicAdd(&bns[D + c], t);
        }
    }
}

// ---------------- BN finalize ----------------
__global__ void k_bnfin(const float* __restrict__ sums, const float* __restrict__ g,
                        const float* __restrict__ b, float* __restrict__ sc,
                        float* __restrict__ sh) {
    int c = threadIdx.x;  // 512
    float mu = sums[c] * (1.0f / NN);
    float var = fmaxf(sums[D + c] * (1.0f / NN) - mu * mu, 0.0f);
    float rstd = rsqrtf(var + EPS);
    float scale = rstd * g[c];
    sc[c] = scale;
    sh[c] = b[c] - mu * scale;
}

// ------- BN apply + relu + pool; write h as hi/lo bf16 pair (internal) ------
__global__ void k_final(const float* __restrict__ accb, const float* __restrict__ sc,
                        const float* __restrict__ sh, const int* __restrict__ batch,
                        u16* __restrict__ hh, u16* __restrict__ hl,
                        float* __restrict__ pool) {
    int t = threadIdx.x; int c = 2 * t;
    long n0 = (long)blockIdx.x * 256;
    float s0 = sc[c], s1 = sc[c + 1], h0 = sh[c], h1 = sh[c + 1];
    float p0 = 0, p1 = 0; int gc = -1;
    for (int rI = 0; rI < 256; rI++) {
        long n = n0 + rI; if (n >= NN) break;
        float2 v = *(const float2*)(accb + (size_t)n * D + c);
        float a = fmaxf(fmaf(v.x, s0, h0), 0.0f);
        float b = fmaxf(fmaf(v.y, s1, h1), 0.0f);
        u16 ah, al, bh, bl;
        split2(a, ah, al); split2(b, bh, bl);
        ((u32*)(hh + (size_t)n * D))[t] = (u32)ah | ((u32)bh << 16);
        ((u32*)(hl + (size_t)n * D))[t] = (u32)al | ((u32)bl << 16);
        int g = batch[n];
        if (g != gc) {
            if (gc >= 0) { atomicAdd(&pool[gc * D + c], p0); atomicAdd(&pool[gc * D + c + 1], p1); }
            gc = g; p0 = 0; p1 = 0;
        }
        p0 += a; p1 += b;
    }
    if (gc >= 0) { atomicAdd(&pool[gc * D + c], p0); atomicAdd(&pool[gc * D + c + 1], p1); }
}

// ---------------- BN apply, write d_out fp32 (last layer) ----------------
__global__ void k_finalout(const float* __restrict__ accb, const float* __restrict__ sc,
                           const float* __restrict__ sh, float* __restrict__ out) {
    int t = threadIdx.x; int c = 2 * t;
    long n0 = (long)blockIdx.x * 256;
    float s0 = sc[c], s1 = sc[c + 1], h0 = sh[c], h1 = sh[c + 1];
    for (int rI = 0; rI < 256; rI++) {
        long n = n0 + rI; if (n >= NN) break;
        float2 v = *(const float2*)(accb + (size_t)n * D + c);
        ((float2*)out)[n * 256 + t] = make_float2(fmaf(v.x, s0, h0), fmaf(v.y, s1, h1));
    }
}

// ---------------- virtual-node MLP (fp32) ----------------
__global__ void k_mlp1(const float* __restrict__ vn, const float* __restrict__ pool,
                       const float* __restrict__ w1, const float* __restrict__ b1,
                       float* __restrict__ u) {
    int g = blockIdx.x >> 2;
    int j = ((blockIdx.x & 3) << 8) | threadIdx.x;
    __shared__ float sv[D];
    int t = threadIdx.x;
    sv[t] = vn[g * D + t] + pool[g * D + t];
    sv[t + 256] = vn[g * D + t + 256] + pool[g * D + t + 256];
    __syncthreads();
    float acc = b1[j];
    for (int k = 0; k < D; k++) acc = fmaf(sv[k], w1[(size_t)k * 2 * D + j], acc);
    u[(size_t)g * 2 * D + j] = acc;
}
__global__ void k_mbn(const float* __restrict__ u, const float* __restrict__ mg,
                      const float* __restrict__ mb, float* __restrict__ z) {
    int j = blockIdx.x * 256 + threadIdx.x;  // 1024 total
    float s = 0, q = 0;
    for (int g = 0; g < G; g++) { float v = u[(size_t)g * 2 * D + j]; s += v; q = fmaf(v, v, q); }
    float mu = s * (1.0f / G);
    float var = fmaxf(q * (1.0f / G) - mu * mu, 0.0f);
    float rstd = rsqrtf(var + EPS);
    float sc = rstd * mg[j];
    float sh = mb[j] - mu * sc;
    for (int g = 0; g < G; g++)
        z[(size_t)g * 2 * D + j] = fmaxf(fmaf(u[(size_t)g * 2 * D + j], sc, sh), 0.0f);
}
__global__ void k_mlp2(const float* __restrict__ z, const float* __restrict__ w2,
                       const float* __restrict__ b2, float* __restrict__ vn) {
    int g = blockIdx.x >> 1;
    int c = ((blockIdx.x & 1) << 8) | threadIdx.x;
    __shared__ float sz[2 * D];
    int t = threadIdx.x;
    #pragma unroll
    for (int i = 0; i < 4; i++) sz[t + i * 256] = z[(size_t)g * 2 * D + t + i * 256];
    __syncthreads();
    float acc = b2[c];
    for (int k = 0; k < 2 * D; k++) acc = fmaf(sz[k], w2[(size_t)k * D + c], acc);
    vn[g * D + c] = acc;
}

extern "C" void kernel_launch(void* const* d_in, const int* in_sizes, int n_in,
                              void* d_out, int out_size, void* d_ws, size_t ws_size,
                              hipStream_t stream) {
    (void)in_sizes; (void)n_in; (void)out_size; (void)ws_size;
    const int*   x     = (const int*)d_in[0];
    const int*   ndep  = (const int*)d_in[1];
    const int*   ei    = (const int*)d_in[2];
    const int*   batch = (const int*)d_in[3];
    const float* ea    = (const float*)d_in[4];
    const float* te    = (const float*)d_in[5];
    const float* ae    = (const float*)d_in[6];
    const float* de    = (const float*)d_in[7];
    const float* vw    = (const float*)d_in[8];
    const float* lw    = (const float*)d_in[9];
    const float* lb    = (const float*)d_in[10];
    const float* cb    = (const float*)d_in[11];
    const float* ew    = (const float*)d_in[12];
    const float* ebp   = (const float*)d_in[13];
    const float* bng   = (const float*)d_in[14];
    const float* bnb   = (const float*)d_in[15];
    const float* mw1   = (const float*)d_in[16];
    const float* mb1   = (const float*)d_in[17];
    const float* mg    = (const float*)d_in[18];
    const float* mbb   = (const float*)d_in[19];
    const float* mw2   = (const float*)d_in[20];
    const float* mb2   = (const float*)d_in[21];

    char* ws = (char*)d_ws;
    size_t off_ = 0;
    auto alloc = [&](size_t b) { size_t o = off_; off_ += (b + 255) & ~(size_t)255; return o; };
    u16*  hh   = (u16*)(ws + alloc((size_t)NN * D * 2));
    u16*  hl   = (u16*)(ws + alloc((size_t)NN * D * 2));
    float* hx  = (float*)(ws + alloc((size_t)NN * D * 4));
    float* acc = (float*)(ws + alloc((size_t)NN * D * 4));
    u16*  Wth  = (u16*)(ws + alloc((size_t)L * D * D * 2));
    u16*  Wtl  = (u16*)(ws + alloc((size_t)L * D * D * 2));
    float* vnW = (float*)(ws + alloc((size_t)G * D * 4));
    float* vn  = (float*)(ws + alloc((size_t)G * D * 4));
    float* pool= (float*)(ws + alloc((size_t)G * D * 4));
    float* u   = (float*)(ws + alloc((size_t)G * 2 * D * 4));
    float* z   = (float*)(ws + alloc((size_t)G * 2 * D * 4));
    float* deg = (float*)(ws + alloc((size_t)NN * 4));
    float* dis = (float*)(ws + alloc((size_t)NN * 4));
    int* degint= (int*)(ws + alloc((size_t)NN * 4));
    float* bns = (float*)(ws + alloc((size_t)2 * D * 4));
    float* bsc = (float*)(ws + alloc((size_t)D * 4));
    float* bsh = (float*)(ws + alloc((size_t)D * 4));
    // CSR-by-destination structures (graph is layer-invariant -> build once)
    int* incnt  = (int*)(ws + alloc((size_t)NN * 4));
    int* offp   = (int*)(ws + alloc((size_t)NN * 4));
    int* cursor = (int*)(ws + alloc((size_t)NN * 4));
    int* bsum   = (int*)(ws + alloc((size_t)1024 * 4));
    int* boff   = (int*)(ws + alloc((size_t)1024 * 4));
    float4* elist = (float4*)(ws + alloc((size_t)NE * 16));

    const int* row = ei;
    const int* colp = ei + NE;

    k_zero<<<(NN + 255) / 256, 256, 0, stream>>>((float*)degint, NN);
    k_deg_count<<<(NE + 255) / 256, 256, 0, stream>>>(row, degint);
    k_deg_fin<<<(NN + 255) / 256, 256, 0, stream>>>(degint, deg, dis);

    // build destination CSR (once)
    k_zero<<<(NN + 255) / 256, 256, 0, stream>>>((float*)incnt, NN);
    k_incount<<<(NE + 255) / 256, 256, 0, stream>>>(colp, incnt);
    k_scan1<<<NB, 256, 0, stream>>>(incnt, bsum);
    k_scan2<<<1, 1024, 0, stream>>>(bsum, boff);
    k_scan3<<<NB, 256, 0, stream>>>(incnt, boff, offp, cursor);
    k_fill<<<(NE + 255) / 256, 256, 0, stream>>>(row, colp, ea, dis, cursor, elist);

    k_encoder<<<NN, 256, 0, stream>>>(x, ndep, te, ae, de, hh, hl);
    k_wsplit<<<dim3(16, 16, L), dim3(32, 8), 0, stream>>>(lw, Wth, Wtl);
    k_vninit<<<G * D / 256, 256, 0, stream>>>(vw, vn);

    for (int l = 0; l < L; l++) {
        k_vnw<<<G, 512, 0, stream>>>(vn, lw + (size_t)l * D * D, lb + (size_t)l * D, vnW);
        k_gemm3<<<dim3(4688), 256, 0, stream>>>(
            hh, hl, Wth + (size_t)l * D * D, Wtl + (size_t)l * D * D, vnW, batch, hx);
        k_zero<<<4, 256, 0, stream>>>(bns, 2 * D);
        k_aggr<<<2048, 256, 0, stream>>>(offp, incnt, elist, hx, cb + (size_t)l * D,
                                         deg, ew + (size_t)l * 2 * D,
                                         ebp + (size_t)l * D, acc, bns);
        k_bnfin<<<1, D, 0, stream>>>(bns, bng + (size_t)l * D, bnb + (size_t)l * D, bsc, bsh);
        if (l < L - 1) {
            k_zero<<<G * D / 256, 256, 0, stream>>>(pool, G * D);
            k_final<<<(NN + 255) / 256, 256, 0, stream>>>(acc, bsc, bsh, batch, hh, hl, pool);
            k_mlp1<<<G * 4, 256, 0, stream>>>(vn, pool, mw1 + (size_t)l * D * 2 * D,
                                              mb1 + (size_t)l * 2 * D, u);
            k_mbn<<<4, 256, 0, stream>>>(u, mg + (size_t)l * 2 * D, mbb + (size_t)l * 2 * D, z);
            k_mlp2<<<G * 2, 256, 0, stream>>>(z, mw2 + (size_t)l * 2 * D * D,
                                              mb2 + (size_t)l * D, vn);
        } else {
            k_finalout<<<(NN + 255) / 256, 256, 0, stream>>>(acc, bsc, bsh, (float*)d_out);
        }
    }
}

// Round 4
// 6268.929 us; speedup vs baseline: 2.9762x; 1.4240x over previous
//
#include <hip/hip_runtime.h>
#include <hip/hip_bf16.h>
#include <stdint.h>

#define NN 150000
#define NE 150000
#define G 128
#define D 512
#define L 5
#define MAXD 20
#define EPS 1e-5f
#define NB ((NN + 255) / 256)

typedef unsigned short u16;
typedef unsigned int u32;
typedef __attribute__((ext_vector_type(8))) short bf16x8;
typedef __attribute__((ext_vector_type(4))) float f32x4;

__device__ __forceinline__ float bf2f(u16 u) {
    union { u32 i; float f; } v; v.i = ((u32)u) << 16; return v.f;
}
__device__ __forceinline__ u16 f2bf(float f) {
    union { float f; u32 i; } v; v.f = f;
    u32 r = v.i + 0x7FFF + ((v.i >> 16) & 1);
    return (u16)(r >> 16);
}
// split fp32 -> (hi, lo) bf16 pair
__device__ __forceinline__ void split2(float v, u16& hi, u16& lo) {
    hi = f2bf(v);
    lo = f2bf(v - bf2f(hi));
}

// async global->LDS, 16B per lane, lds dest = wave-uniform base + lane*16
__device__ __forceinline__ void gload(const u16* g, u16* l) {
    __builtin_amdgcn_global_load_lds(
        (const __attribute__((address_space(1))) unsigned int*)g,
        (__attribute__((address_space(3))) unsigned int*)l, 16, 0, 0);
}

// ---------------- zero fill ----------------
__global__ void k_zero(float* __restrict__ p, int n) {
    int i = blockIdx.x * 256 + threadIdx.x;
    if (i < n) p[i] = 0.0f;
}

// ---------------- degree (out-degree by row, used for norm + self term) ----
__global__ void k_deg_count(const int* __restrict__ row, int* __restrict__ degint) {
    int e = blockIdx.x * 256 + threadIdx.x;
    if (e < NE) atomicAdd(&degint[row[e]], 1);
}
__global__ void k_deg_fin(const int* __restrict__ degint, float* __restrict__ deg,
                          float* __restrict__ dis) {
    int n = blockIdx.x * 256 + threadIdx.x;
    if (n < NN) {
        float d = (float)degint[n] + 1.0f;
        deg[n] = d;
        dis[n] = rsqrtf(d);
    }
}

// ---------------- CSR build by destination (col) -----------------------------
__global__ void k_incount(const int* __restrict__ col, int* __restrict__ incnt) {
    int e = blockIdx.x * 256 + threadIdx.x;
    if (e < NE) atomicAdd(&incnt[col[e]], 1);
}
__global__ void k_scan1(const int* __restrict__ incnt, int* __restrict__ bsum) {
    __shared__ int sm[256];
    int b = blockIdx.x, t = threadIdx.x;
    int n = b * 256 + t;
    sm[t] = (n < NN) ? incnt[n] : 0;
    __syncthreads();
    #pragma unroll
    for (int s = 128; s > 0; s >>= 1) {
        if (t < s) sm[t] += sm[t + s];
        __syncthreads();
    }
    if (t == 0) bsum[b] = sm[0];
}
__global__ void k_scan2(const int* __restrict__ bsum, int* __restrict__ boff) {
    __shared__ int sm[1024];
    int t = threadIdx.x;
    int v0 = (t < NB) ? bsum[t] : 0;
    sm[t] = v0;
    __syncthreads();
    #pragma unroll
    for (int s = 1; s < 1024; s <<= 1) {
        int v = (t >= s) ? sm[t - s] : 0;
        __syncthreads();
        sm[t] += v;
        __syncthreads();
    }
    if (t < NB) boff[t] = sm[t] - v0;  // exclusive
}
__global__ void k_scan3(const int* __restrict__ incnt, const int* __restrict__ boff,
                        int* __restrict__ off, int* __restrict__ cursor) {
    __shared__ int sm[256];
    int b = blockIdx.x, t = threadIdx.x;
    int n = b * 256 + t;
    int c = (n < NN) ? incnt[n] : 0;
    sm[t] = c;
    __syncthreads();
    #pragma unroll
    for (int s = 1; s < 256; s <<= 1) {
        int v = (t >= s) ? sm[t - s] : 0;
        __syncthreads();
        sm[t] += v;
        __syncthreads();
    }
    if (n < NN) {
        int ex = boff[b] + sm[t] - c;
        off[n] = ex;
        cursor[n] = ex;
    }
}
// elist entry: (src as int bits, norm, a0, a1)
__global__ void k_fill(const int* __restrict__ row, const int* __restrict__ col,
                       const float* __restrict__ ea, const float* __restrict__ dis,
                       int* __restrict__ cursor, float4* __restrict__ elist) {
    int e = blockIdx.x * 256 + threadIdx.x;
    if (e >= NE) return;
    int r = row[e], c = col[e];
    int pos = atomicAdd(&cursor[c], 1);
    float4 v;
    v.x = __int_as_float(r);
    v.y = dis[r] * dis[c];
    v.z = ea[2 * e];
    v.w = ea[2 * e + 1];
    elist[pos] = v;
}

// ---------------- node encoder (fp32 in, hi/lo bf16 out) ----------------
__global__ void k_encoder(const int* __restrict__ x, const int* __restrict__ dep,
                          const float* __restrict__ te, const float* __restrict__ ae,
                          const float* __restrict__ de,
                          u16* __restrict__ hh, u16* __restrict__ hl) {
    int n = blockIdx.x, t = threadIdx.x;  // 256 threads, 2 cols each
    int t0 = x[2 * n], t1 = x[2 * n + 1];
    int dp = dep[n]; if (dp > MAXD) dp = MAXD;
    float2 a = ((const float2*)(te + (size_t)t0 * D))[t];
    float2 b = ((const float2*)(ae + (size_t)t1 * D))[t];
    float2 c = ((const float2*)(de + (size_t)dp * D))[t];
    float v0 = a.x + b.x + c.x;
    float v1 = a.y + b.y + c.y;
    u16 h0, l0, h1, l1;
    split2(v0, h0, l0); split2(v1, h1, l1);
    ((u32*)(hh + (size_t)n * D))[t] = (u32)h0 | ((u32)h1 << 16);
    ((u32*)(hl + (size_t)n * D))[t] = (u32)l0 | ((u32)l1 << 16);
}

// -------- transpose+split lin_w: Wh/Wl[l][n][k] = split(W[l][k][n]) --------
__global__ void k_wsplit(const float* __restrict__ W, u16* __restrict__ Wh,
                         u16* __restrict__ Wl) {
    __shared__ float tile[32][33];
    int l = blockIdx.z, kt = blockIdx.y, nt = blockIdx.x;
    const float* Wlp = W + (size_t)l * D * D;
    int tx = threadIdx.x, ty = threadIdx.y;  // 32 x 8
    #pragma unroll
    for (int i = 0; i < 32; i += 8)
        tile[ty + i][tx] = Wlp[(size_t)(kt * 32 + ty + i) * D + nt * 32 + tx];
    __syncthreads();
    #pragma unroll
    for (int i = 0; i < 32; i += 8) {
        float v = tile[tx][ty + i];
        u16 hi, lo; split2(v, hi, lo);
        size_t o = (size_t)l * D * D + (size_t)(nt * 32 + ty + i) * D + kt * 32 + tx;
        Wh[o] = hi; Wl[o] = lo;
    }
}

// ---------------- vn init ----------------
__global__ void k_vninit(const float* __restrict__ vw, float* __restrict__ vn) {
    int i = blockIdx.x * 256 + threadIdx.x;
    vn[i] = vw[i & (D - 1)];
}

// ---------------- vnW = vn @ W + lin_b (fp32, tiny) ----------------
__global__ void k_vnw(const float* __restrict__ vn, const float* __restrict__ W,
                      const float* __restrict__ lb, float* __restrict__ vnW) {
    int g = blockIdx.x, c = threadIdx.x;  // 512 threads
    __shared__ float sv[D];
    sv[c] = vn[g * D + c];
    __syncthreads();
    float acc = lb[c];
    for (int k = 0; k < D; k++) acc = fmaf(sv[k], W[(size_t)k * D + c], acc);
    vnW[g * D + c] = acc;
}

// ------- split-bf16 GEMM: hx = (hh+hl) @ (Wh+Wl)^T_layout + vnW[batch] -----
// 3 MFMA products per tile: Ah*Bh + Ah*Bl + Al*Bh (Al*Bl dropped, ~2^-18)
// Staging: global_load_lds width=16, plane-major LDS tiles [4][128][8] u16
//   (linear in wave order -> legal for global_load_lds; fragment ds_read_b128
//    becomes 16B-stride row-consecutive -> bank-conflict-free).
// Epilogue: LDS fragment transpose (XOR-swizzled addr only) -> float4 stores.
// Grid: 1-D 4688 with bijective XCD-chunked swizzle, col-block fastest.
__global__ __launch_bounds__(256) void k_gemm3(
    const u16* __restrict__ Ahp, const u16* __restrict__ Alp,
    const u16* __restrict__ Bhp, const u16* __restrict__ Blp,
    const float* __restrict__ vnW, const int* __restrict__ batch,
    float* __restrict__ hx) {
    __shared__ __align__(16) u16 smem[4 * 4096];   // 32 KB, reused by epilogue
    u16* sAh = smem;            // [plane 0..3][row 0..127][8 u16]
    u16* sAl = smem + 4096;
    u16* sBh = smem + 8192;
    u16* sBl = smem + 12288;

    const int tid = threadIdx.x;
    const int wave = tid >> 6, ln = tid & 63;

    // XCD-aware swizzle: 4688 = 8 * 586; y (col-block) fastest within chunk
    int wg = blockIdx.x;
    int gid = (wg & 7) * 586 + (wg >> 3);
    const long row0 = (long)(gid >> 2) * 128;
    const int col0 = (gid & 3) * 128;

    f32x4 acc[4][4] = {};
    const int wm = wave & 1, wn = wave >> 1;
    const int lrow = ln & 15, lq = ln >> 4;

    // staging chunks: chunk c covers LDS bytes [c*16, c*16+16) = plane c>>7, row c&127
    const int c1 = tid, c2 = tid + 256;
    long ar1 = row0 + (c1 & 127); if (ar1 >= NN) ar1 = NN - 1;  // clamp (stores guarded)
    long ar2 = row0 + (c2 & 127); if (ar2 >= NN) ar2 = NN - 1;
    const size_t aoff1 = (size_t)ar1 * D + (c1 >> 7) * 8;
    const size_t aoff2 = (size_t)ar2 * D + (c2 >> 7) * 8;
    const size_t boff1 = (size_t)(col0 + (c1 & 127)) * D + (c1 >> 7) * 8;
    const size_t boff2 = (size_t)(col0 + (c2 & 127)) * D + (c2 >> 7) * 8;
    u16* lA1 = sAh + c1 * 8;  u16* lA2 = sAh + c2 * 8;
    u16* lB1 = sAl + c1 * 8;  u16* lB2 = sAl + c2 * 8;
    u16* lC1 = sBh + c1 * 8;  u16* lC2 = sBh + c2 * 8;
    u16* lD1 = sBl + c1 * 8;  u16* lD2 = sBl + c2 * 8;

    for (int kt = 0; kt < D / 32; ++kt) {
        const int ks = kt * 32;
        __syncthreads();                  // prev iteration's frag reads done
        gload(Ahp + aoff1 + ks, lA1);
        gload(Ahp + aoff2 + ks, lA2);
        gload(Alp + aoff1 + ks, lB1);
        gload(Alp + aoff2 + ks, lB2);
        gload(Bhp + boff1 + ks, lC1);
        gload(Bhp + boff2 + ks, lC2);
        gload(Blp + boff1 + ks, lD1);
        gload(Blp + boff2 + ks, lD2);
        __syncthreads();                  // drains vmcnt -> tiles visible

        bf16x8 ah[4], al[4], bh[4], bl[4];
        #pragma unroll
        for (int i = 0; i < 4; i++) {
            int ra = wm * 64 + i * 16 + lrow;
            int rb = wn * 64 + i * 16 + lrow;
            ah[i] = *(const bf16x8*)&sAh[lq * 1024 + ra * 8];
            al[i] = *(const bf16x8*)&sAl[lq * 1024 + ra * 8];
            bh[i] = *(const bf16x8*)&sBh[lq * 1024 + rb * 8];
            bl[i] = *(const bf16x8*)&sBl[lq * 1024 + rb * 8];
        }
        #pragma unroll
        for (int i = 0; i < 4; i++) {
            #pragma unroll
            for (int j = 0; j < 4; j++) {
                acc[i][j] = __builtin_amdgcn_mfma_f32_16x16x32_bf16(ah[i], bh[j], acc[i][j], 0, 0, 0);
                acc[i][j] = __builtin_amdgcn_mfma_f32_16x16x32_bf16(ah[i], bl[j], acc[i][j], 0, 0, 0);
                acc[i][j] = __builtin_amdgcn_mfma_f32_16x16x32_bf16(al[i], bh[j], acc[i][j], 0, 0, 0);
            }
        }
    }

    // ---- epilogue: transpose fragments via LDS, store float4 per lane ----
    // C/D layout per 16x16 frag: col = lane&15, row = (lane>>4)*4 + reg
    __syncthreads();                       // staging reads done; safe to reuse LDS
    float* fsm = (float*)smem;
    const int ep_off = wave * (32 * 64);   // 8 KB per wave, 32 KB total
    const int rg = ln >> 4, cl = ln & 15;  // read-back: 16 lanes/row, 4 rows/instr
    #pragma unroll
    for (int ip = 0; ip < 2; ip++) {
        #pragma unroll
        for (int i2 = 0; i2 < 2; i2++) {
            int i = ip * 2 + i2;
            #pragma unroll
            for (int j = 0; j < 4; j++) {
                #pragma unroll
                for (int r = 0; r < 4; r++) {
                    int srow = i2 * 16 + lq * 4 + r;
                    int m = (srow >> 2) & 3;            // XOR swizzle: kill 4-way write conflict
                    fsm[ep_off + srow * 64 + ((j ^ m) * 16) + lrow] = acc[i][j][r];
                }
            }
        }
        // same-wave LDS read-back (compiler inserts lgkmcnt waits)
        #pragma unroll
        for (int rr = 0; rr < 8; rr++) {
            int lr = rr * 4 + rg;          // local row 0..31
            int m = (lr >> 2) & 3;
            int sgrp = (cl >> 2) ^ m;      // swizzled SLOT group (address only)
            long R = row0 + wm * 64 + ip * 32 + lr;
            if (R < NN) {
                float4 v = *(const float4*)&fsm[ep_off + lr * 64 + sgrp * 16 + (cl & 3) * 4];
                int Cc = col0 + wn * 64 + cl * 4;   // ACTUAL column (bugfix: was sgrp-based)
                int g = batch[R];
                const float* vb = vnW + (size_t)g * D + Cc;
                float4 b4 = *(const float4*)vb;
                v.x += b4.x; v.y += b4.y; v.z += b4.z; v.w += b4.w;
                *(float4*)(hx + (size_t)R * D + Cc) = v;
            }
        }
        if (ip == 0) __syncthreads();      // per-wave regions; cheap safety
    }
}

// ------- fused aggregate: acc[n] = relu(hx[n]+cb)/deg[n]
//                                 + sum_{e: col[e]==n} nrm_e * relu(hx[row_e] + ee_e)
// also accumulates BN sum/sumsq (block-reduced in LDS, 1 atomic/col/block) -----
__global__ __launch_bounds__(256) void k_aggr(
    const int* __restrict__ off, const int* __restrict__ cnt,
    const float4* __restrict__ elist, const float* __restrict__ hx,
    const float* __restrict__ cb, const float* __restrict__ deg,
    const float* __restrict__ ew, const float* __restrict__ eb,
    float* __restrict__ out, float* __restrict__ bns) {
    const int lane = threadIdx.x & 63;
    const int wv = threadIdx.x >> 6;
    const int gw = blockIdx.x * 4 + wv;
    const int nwaves = gridDim.x * 4;
    const int c0 = lane * 8;

    float w0[8], w1[8], bb[8], cbv[8];
    *(float4*)&w0[0] = *(const float4*)(ew + c0);
    *(float4*)&w0[4] = *(const float4*)(ew + c0 + 4);
    *(float4*)&w1[0] = *(const float4*)(ew + D + c0);
    *(float4*)&w1[4] = *(const float4*)(ew + D + c0 + 4);
    *(float4*)&bb[0] = *(const float4*)(eb + c0);
    *(float4*)&bb[4] = *(const float4*)(eb + c0 + 4);
    *(float4*)&cbv[0] = *(const float4*)(cb + c0);
    *(float4*)&cbv[4] = *(const float4*)(cb + c0 + 4);

    float s[8] = {}, q[8] = {};

    for (int n = gw; n < NN; n += nwaves) {
        float a[8];
        const float* hp = hx + (size_t)n * D + c0;
        *(float4*)&a[0] = *(const float4*)(hp);
        *(float4*)&a[4] = *(const float4*)(hp + 4);
        float invd = 1.0f / deg[n];
        float acc8[8];
        #pragma unroll
        for (int j = 0; j < 8; j++) acc8[j] = fmaxf(a[j] + cbv[j], 0.0f) * invd;

        int k0 = off[n], k1 = k0 + cnt[n];
        for (int k = k0; k < k1; k++) {
            float4 m = elist[k];
            int r = __float_as_int(m.x);
            const float* hr = hx + (size_t)r * D + c0;
            float hf[8];
            *(float4*)&hf[0] = *(const float4*)(hr);
            *(float4*)&hf[4] = *(const float4*)(hr + 4);
            #pragma unroll
            for (int j = 0; j < 8; j++)
                acc8[j] = fmaf(m.y, fmaxf(hf[j] + fmaf(m.z, w0[j], fmaf(m.w, w1[j], bb[j])), 0.0f), acc8[j]);
        }
        float* op = out + (size_t)n * D + c0;
        *(float4*)(op) = *(const float4*)&acc8[0];
        *(float4*)(op + 4) = *(const float4*)&acc8[4];
        #pragma unroll
        for (int j = 0; j < 8; j++) {
            s[j] += acc8[j];
            q[j] = fmaf(acc8[j], acc8[j], q[j]);
        }
    }

    // block-level BN reduction: 4 waves share the same column mapping
    __shared__ float red[4][512];
    #pragma unroll
    for (int j = 0; j < 8; j++) red[wv][c0 + j] = s[j];
    __syncthreads();
    if (wv == 0) {
        #pragma unroll
        for (int j = 0; j < 8; j++) {
            int c = c0 + j;
            float t = red[0][c] + red[1][c] + red[2][c] + red[3][c];
            atomicAdd(&bns[c], t);
        }
    }
    __syncthreads();
    #pragma unroll
    for (int j = 0; j < 8; j++) red[wv][c0 + j] = q[j];
    __syncthreads();
    if (wv == 0) {
        #pragma unroll
        for (int j = 0; j < 8; j++) {
            int c = c0 + j;
            float t = red[0][c] + red[1][c] + red[2][c] + red[3][c];
            atomicAdd(&bns[D + c], t);
        }
    }
}

// ---------------- BN finalize ----------------
__global__ void k_bnfin(const float* __restrict__ sums, const float* __restrict__ g,
                        const float* __restrict__ b, float* __restrict__ sc,
                        float* __restrict__ sh) {
    int c = threadIdx.x;  // 512
    float mu = sums[c] * (1.0f / NN);
    float var = fmaxf(sums[D + c] * (1.0f / NN) - mu * mu, 0.0f);
    float rstd = rsqrtf(var + EPS);
    float scale = rstd * g[c];
    sc[c] = scale;
    sh[c] = b[c] - mu * scale;
}

// ------- BN apply + relu + pool; write h as hi/lo bf16 pair (internal) ------
__global__ void k_final(const float* __restrict__ accb, const float* __restrict__ sc,
                        const float* __restrict__ sh, const int* __restrict__ batch,
                        u16* __restrict__ hh, u16* __restrict__ hl,
                        float* __restrict__ pool) {
    int t = threadIdx.x; int c = 2 * t;
    long n0 = (long)blockIdx.x * 256;
    float s0 = sc[c], s1 = sc[c + 1], h0 = sh[c], h1 = sh[c + 1];
    float p0 = 0, p1 = 0; int gc = -1;
    for (int rI = 0; rI < 256; rI++) {
        long n = n0 + rI; if (n >= NN) break;
        float2 v = *(const float2*)(accb + (size_t)n * D + c);
        float a = fmaxf(fmaf(v.x, s0, h0), 0.0f);
        float b = fmaxf(fmaf(v.y, s1, h1), 0.0f);
        u16 ah, al, bh, bl;
        split2(a, ah, al); split2(b, bh, bl);
        ((u32*)(hh + (size_t)n * D))[t] = (u32)ah | ((u32)bh << 16);
        ((u32*)(hl + (size_t)n * D))[t] = (u32)al | ((u32)bl << 16);
        int g = batch[n];
        if (g != gc) {
            if (gc >= 0) { atomicAdd(&pool[gc * D + c], p0); atomicAdd(&pool[gc * D + c + 1], p1); }
            gc = g; p0 = 0; p1 = 0;
        }
        p0 += a; p1 += b;
    }
    if (gc >= 0) { atomicAdd(&pool[gc * D + c], p0); atomicAdd(&pool[gc * D + c + 1], p1); }
}

// ---------------- BN apply, write d_out fp32 (last layer) ----------------
__global__ void k_finalout(const float* __restrict__ accb, const float* __restrict__ sc,
                           const float* __restrict__ sh, float* __restrict__ out) {
    int t = threadIdx.x; int c = 2 * t;
    long n0 = (long)blockIdx.x * 256;
    float s0 = sc[c], s1 = sc[c + 1], h0 = sh[c], h1 = sh[c + 1];
    for (int rI = 0; rI < 256; rI++) {
        long n = n0 + rI; if (n >= NN) break;
        float2 v = *(const float2*)(accb + (size_t)n * D + c);
        ((float2*)out)[n * 256 + t] = make_float2(fmaf(v.x, s0, h0), fmaf(v.y, s1, h1));
    }
}

// ---------------- virtual-node MLP (fp32) ----------------
__global__ void k_mlp1(const float* __restrict__ vn, const float* __restrict__ pool,
                       const float* __restrict__ w1, const float* __restrict__ b1,
                       float* __restrict__ u) {
    int g = blockIdx.x >> 2;
    int j = ((blockIdx.x & 3) << 8) | threadIdx.x;
    __shared__ float sv[D];
    int t = threadIdx.x;
    sv[t] = vn[g * D + t] + pool[g * D + t];
    sv[t + 256] = vn[g * D + t + 256] + pool[g * D + t + 256];
    __syncthreads();
    float acc = b1[j];
    for (int k = 0; k < D; k++) acc = fmaf(sv[k], w1[(size_t)k * 2 * D + j], acc);
    u[(size_t)g * 2 * D + j] = acc;
}
__global__ void k_mbn(const float* __restrict__ u, const float* __restrict__ mg,
                      const float* __restrict__ mb, float* __restrict__ z) {
    int j = blockIdx.x * 256 + threadIdx.x;  // 1024 total
    float s = 0, q = 0;
    for (int g = 0; g < G; g++) { float v = u[(size_t)g * 2 * D + j]; s += v; q = fmaf(v, v, q); }
    float mu = s * (1.0f / G);
    float var = fmaxf(q * (1.0f / G) - mu * mu, 0.0f);
    float rstd = rsqrtf(var + EPS);
    float sc = rstd * mg[j];
    float sh = mb[j] - mu * sc;
    for (int g = 0; g < G; g++)
        z[(size_t)g * 2 * D + j] = fmaxf(fmaf(u[(size_t)g * 2 * D + j], sc, sh), 0.0f);
}
__global__ void k_mlp2(const float* __restrict__ z, const float* __restrict__ w2,
                       const float* __restrict__ b2, float* __restrict__ vn) {
    int g = blockIdx.x >> 1;
    int c = ((blockIdx.x & 1) << 8) | threadIdx.x;
    __shared__ float sz[2 * D];
    int t = threadIdx.x;
    #pragma unroll
    for (int i = 0; i < 4; i++) sz[t + i * 256] = z[(size_t)g * 2 * D + t + i * 256];
    __syncthreads();
    float acc = b2[c];
    for (int k = 0; k < 2 * D; k++) acc = fmaf(sz[k], w2[(size_t)k * D + c], acc);
    vn[g * D + c] = acc;
}

extern "C" void kernel_launch(void* const* d_in, const int* in_sizes, int n_in,
                              void* d_out, int out_size, void* d_ws, size_t ws_size,
                              hipStream_t stream) {
    (void)in_sizes; (void)n_in; (void)out_size; (void)ws_size;
    const int*   x     = (const int*)d_in[0];
    const int*   ndep  = (const int*)d_in[1];
    const int*   ei    = (const int*)d_in[2];
    const int*   batch = (const int*)d_in[3];
    const float* ea    = (const float*)d_in[4];
    const float* te    = (const float*)d_in[5];
    const float* ae    = (const float*)d_in[6];
    const float* de    = (const float*)d_in[7];
    const float* vw    = (const float*)d_in[8];
    const float* lw    = (const float*)d_in[9];
    const float* lb    = (const float*)d_in[10];
    const float* cb    = (const float*)d_in[11];
    const float* ew    = (const float*)d_in[12];
    const float* ebp   = (const float*)d_in[13];
    const float* bng   = (const float*)d_in[14];
    const float* bnb   = (const float*)d_in[15];
    const float* mw1   = (const float*)d_in[16];
    const float* mb1   = (const float*)d_in[17];
    const float* mg    = (const float*)d_in[18];
    const float* mbb   = (const float*)d_in[19];
    const float* mw2   = (const float*)d_in[20];
    const float* mb2   = (const float*)d_in[21];

    char* ws = (char*)d_ws;
    size_t off_ = 0;
    auto alloc = [&](size_t b) { size_t o = off_; off_ += (b + 255) & ~(size_t)255; return o; };
    u16*  hh   = (u16*)(ws + alloc((size_t)NN * D * 2));
    u16*  hl   = (u16*)(ws + alloc((size_t)NN * D * 2));
    float* hx  = (float*)(ws + alloc((size_t)NN * D * 4));
    float* acc = (float*)(ws + alloc((size_t)NN * D * 4));
    u16*  Wth  = (u16*)(ws + alloc((size_t)L * D * D * 2));
    u16*  Wtl  = (u16*)(ws + alloc((size_t)L * D * D * 2));
    float* vnW = (float*)(ws + alloc((size_t)G * D * 4));
    float* vn  = (float*)(ws + alloc((size_t)G * D * 4));
    float* pool= (float*)(ws + alloc((size_t)G * D * 4));
    float* u   = (float*)(ws + alloc((size_t)G * 2 * D * 4));
    float* z   = (float*)(ws + alloc((size_t)G * 2 * D * 4));
    float* deg = (float*)(ws + alloc((size_t)NN * 4));
    float* dis = (float*)(ws + alloc((size_t)NN * 4));
    int* degint= (int*)(ws + alloc((size_t)NN * 4));
    float* bns = (float*)(ws + alloc((size_t)2 * D * 4));
    float* bsc = (float*)(ws + alloc((size_t)D * 4));
    float* bsh = (float*)(ws + alloc((size_t)D * 4));
    // CSR-by-destination structures (graph is layer-invariant -> build once)
    int* incnt  = (int*)(ws + alloc((size_t)NN * 4));
    int* offp   = (int*)(ws + alloc((size_t)NN * 4));
    int* cursor = (int*)(ws + alloc((size_t)NN * 4));
    int* bsum   = (int*)(ws + alloc((size_t)1024 * 4));
    int* boff   = (int*)(ws + alloc((size_t)1024 * 4));
    float4* elist = (float4*)(ws + alloc((size_t)NE * 16));

    const int* row = ei;
    const int* colp = ei + NE;

    k_zero<<<(NN + 255) / 256, 256, 0, stream>>>((float*)degint, NN);
    k_deg_count<<<(NE + 255) / 256, 256, 0, stream>>>(row, degint);
    k_deg_fin<<<(NN + 255) / 256, 256, 0, stream>>>(degint, deg, dis);

    // build destination CSR (once)
    k_zero<<<(NN + 255) / 256, 256, 0, stream>>>((float*)incnt, NN);
    k_incount<<<(NE + 255) / 256, 256, 0, stream>>>(colp, incnt);
    k_scan1<<<NB, 256, 0, stream>>>(incnt, bsum);
    k_scan2<<<1, 1024, 0, stream>>>(bsum, boff);
    k_scan3<<<NB, 256, 0, stream>>>(incnt, boff, offp, cursor);
    k_fill<<<(NE + 255) / 256, 256, 0, stream>>>(row, colp, ea, dis, cursor, elist);

    k_encoder<<<NN, 256, 0, stream>>>(x, ndep, te, ae, de, hh, hl);
    k_wsplit<<<dim3(16, 16, L), dim3(32, 8), 0, stream>>>(lw, Wth, Wtl);
    k_vninit<<<G * D / 256, 256, 0, stream>>>(vw, vn);

    for (int l = 0; l < L; l++) {
        k_vnw<<<G, 512, 0, stream>>>(vn, lw + (size_t)l * D * D, lb + (size_t)l * D, vnW);
        k_gemm3<<<dim3(4688), 256, 0, stream>>>(
            hh, hl, Wth + (size_t)l * D * D, Wtl + (size_t)l * D * D, vnW, batch, hx);
        k_zero<<<4, 256, 0, stream>>>(bns, 2 * D);
        k_aggr<<<2048, 256, 0, stream>>>(offp, incnt, elist, hx, cb + (size_t)l * D,
                                         deg, ew + (size_t)l * 2 * D,
                                         ebp + (size_t)l * D, acc, bns);
        k_bnfin<<<1, D, 0, stream>>>(bns, bng + (size_t)l * D, bnb + (size_t)l * D, bsc, bsh);
        if (l < L - 1) {
            k_zero<<<G * D / 256, 256, 0, stream>>>(pool, G * D);
            k_final<<<(NN + 255) / 256, 256, 0, stream>>>(acc, bsc, bsh, batch, hh, hl, pool);
            k_mlp1<<<G * 4, 256, 0, stream>>>(vn, pool, mw1 + (size_t)l * D * 2 * D,
                                              mb1 + (size_t)l * 2 * D, u);
            k_mbn<<<4, 256, 0, stream>>>(u, mg + (size_t)l * 2 * D, mbb + (size_t)l * 2 * D, z);
            k_mlp2<<<G * 2, 256, 0, stream>>>(z, mw2 + (size_t)l * 2 * D * D,
                                              mb2 + (size_t)l * D, vn);
        } else {
            k_finalout<<<(NN + 255) / 256, 256, 0, stream>>>(acc, bsc, bsh, (float*)d_out);
        }
    }
}